// Round 12
// baseline (268.138 us; speedup 1.0000x reference)
//
#include <hip/hip_runtime.h>
#include <hip/hip_bf16.h>

// 3-layer GraphConv (PyG) + softmax, 100k nodes, 1.6M edges, all f32.
// R2:  f32 global atomics ~306G/s scattered -> pull-gather wins.
// R3:  per-node CSR scatter: 16x write amplification (128us).
// R4:  coarse position-returning cursors: same-address serialization (376us).
// R5:  two-phase placement fixed build; transform store-amp found (94us).
// R6:  LDS-weight transform regressed (LDS-issue bound, 133us). Reverted.
// R7:  linear2 (scalar-path weights, register accs) fixed transform.
// R8:  coarse-first build killed hist_node; reservation chains next (49us).
// R9:  fully deterministic build (zero global atomics). gather32 44.5us.
// R10: staged unroll + occupancy: 248.7us; gather is L2-miss floor.
// R11: bf16 messages FAILED precision (0.0996 > 0.02): downstream glorot
//      gains amplify quantization ~20x. f32 is mandatory.
// R12: revert to f32; fuse layer-2/3 linears into gather epilogues (LDS
//      stage relu(h), one output column per lane). -2 launches, -32MB of
//      h round-trip traffic, same math as R10 otherwise.

#define RNODES 128
#define NB_MAX 1024
#define CH 4096            // edges per chunk
#define CMAX 512           // max chunks (scan_chunkhist: one chunk/thread)

// ---------------- gather inner loop (staged unroll 16/4/1) -----------------
template <int F>
__device__ __forceinline__ float gather_sum(const float* __restrict__ tf,
                                            const int* __restrict__ srcs,
                                            int beg, int end) {
    float sum = 0.0f;
    int e = beg;
    for (; e + 16 <= end; e += 16) {
        int s[16];
        float v[16];
#pragma unroll
        for (int u = 0; u < 16; ++u) s[u] = srcs[e + u];
#pragma unroll
        for (int u = 0; u < 16; ++u) v[u] = tf[(long)s[u] * F];
#pragma unroll
        for (int u = 0; u < 16; ++u) sum += v[u];
    }
    for (; e + 4 <= end; e += 4) {
        int s[4];
        float v[4];
#pragma unroll
        for (int u = 0; u < 4; ++u) s[u] = srcs[e + u];
#pragma unroll
        for (int u = 0; u < 4; ++u) v[u] = tf[(long)s[u] * F];
        sum += (v[0] + v[1]) + (v[2] + v[3]);
    }
    for (; e < end; ++e) sum += tf[(long)srcs[e] * F];
    return sum;
}

// ---------------- linear: out = act(x) @ W (+ bias for root task) ----------
// gridDim.y==2: y=0 -> t = act(x)@Wrel ; y=1 -> acc = act(x)@Wroot + b
template <int Fin, int Fout, bool RELU>
__global__ void linear2_kernel(const float* __restrict__ x,
                               const float* __restrict__ Wrel,
                               const float* __restrict__ Wroot,
                               const float* __restrict__ bias,
                               float* __restrict__ t,
                               float* __restrict__ acc, int N) {
    const bool rootTask = (blockIdx.y != 0);
    const float* __restrict__ W = rootTask ? Wroot : Wrel;
    float* __restrict__ outp    = rootTask ? acc : t;

    int n = blockIdx.x * blockDim.x + threadIdx.x;
    if (n >= N) return;

    float o[Fout];
#pragma unroll
    for (int f = 0; f < Fout; ++f) o[f] = 0.f;

    const float* xr = x + (size_t)n * Fin;
    for (int k0 = 0; k0 < Fin; k0 += 16) {
#pragma unroll
        for (int k = 0; k < 16; k += 4) {
            float4 v = *(const float4*)(xr + k0 + k);
            if (RELU) {
                v.x = fmaxf(v.x, 0.f); v.y = fmaxf(v.y, 0.f);
                v.z = fmaxf(v.z, 0.f); v.w = fmaxf(v.w, 0.f);
            }
            const float xv[4] = {v.x, v.y, v.z, v.w};
#pragma unroll
            for (int kk = 0; kk < 4; ++kk) {
                const float* wr = W + (size_t)(k0 + k + kk) * Fout;
#pragma unroll
                for (int f = 0; f < Fout; ++f)
                    o[f] = fmaf(xv[kk], wr[f], o[f]);
            }
        }
    }
    if (rootTask) {
#pragma unroll
        for (int f = 0; f < Fout; ++f) o[f] += bias[f];
    }
    float* op = outp + (size_t)n * Fout;
    if constexpr (Fout >= 4) {
#pragma unroll
        for (int f = 0; f < Fout; f += 4)
            *(float4*)(op + f) = make_float4(o[f], o[f + 1], o[f + 2], o[f + 3]);
    } else {
        *(float2*)op = make_float2(o[0], o[1]);
    }
}

// ---------------- build step 1: per-chunk LDS histogram --------------------
__global__ void hist_chunked_kernel(const int* __restrict__ dst,
                                    int* __restrict__ chunkhist,
                                    int nE, int NB) {
    __shared__ int h[NB_MAX];
    const int c  = blockIdx.x;
    const int e0 = c * CH, e1 = min(e0 + CH, nE);
    for (int b = threadIdx.x; b < NB; b += blockDim.x) h[b] = 0;
    __syncthreads();
    for (int e = e0 + threadIdx.x; e < e1; e += blockDim.x)
        atomicAdd(&h[dst[e] >> 7], 1);
    __syncthreads();
    for (int b = threadIdx.x; b < NB; b += blockDim.x)
        chunkhist[(size_t)c * NB + b] = h[b];
}

// ---------------- build step 2: column scan (per bucket over chunks) -------
__global__ void scan_chunkhist_kernel(int* __restrict__ chunkhist,
                                      int* __restrict__ gtotal,
                                      int C, int NB) {
    __shared__ int s[CMAX];
    const int b = blockIdx.x;
    const int t = threadIdx.x;
    int v = (t < C) ? chunkhist[(size_t)t * NB + b] : 0;
    s[t] = v;
    __syncthreads();
    for (int off = 1; off < CMAX; off <<= 1) {
        int u = (t >= off) ? s[t - off] : 0;
        __syncthreads();
        s[t] += u;
        __syncthreads();
    }
    if (t < C) chunkhist[(size_t)t * NB + b] = s[t] - v;   // exclusive
    if (t == CMAX - 1) gtotal[b] = s[t];
}

// ---------------- build step 3: bucket scan (single block) -----------------
__global__ void scan_buckets_kernel(const int* __restrict__ gtotal,
                                    int* __restrict__ bptr, int NB, int nE) {
    __shared__ int s[NB_MAX];
    int t = threadIdx.x;
    int own = (t < NB) ? gtotal[t] : 0;
    s[t] = own;
    __syncthreads();
    for (int off = 1; off < NB_MAX; off <<= 1) {
        int v = (t >= off) ? s[t - off] : 0;
        __syncthreads();
        s[t] += v;
        __syncthreads();
    }
    if (t < NB) bptr[t] = s[t] - own;
    if (t == 0) bptr[NB] = nE;
}

// ---------------- build step 4: deterministic placement --------------------
__global__ void bucketize_det_kernel(const int* __restrict__ src,
                                     const int* __restrict__ dst,
                                     const int* __restrict__ chunkpre,
                                     const int* __restrict__ bptr,
                                     unsigned int* __restrict__ records,
                                     int nE, int NB) {
    __shared__ int lcur[NB_MAX];
    const int c  = blockIdx.x;
    const int e0 = c * CH, e1 = min(e0 + CH, nE);
    for (int b = threadIdx.x; b < NB; b += blockDim.x)
        lcur[b] = bptr[b] + chunkpre[(size_t)c * NB + b];
    __syncthreads();
    for (int e = e0 + threadIdx.x; e < e1; e += blockDim.x) {
        int d = dst[e];
        int b = d >> 7;
        int pos = atomicAdd(&lcur[b], 1);                  // LDS-only atomic
        records[pos] = (unsigned int)src[e] | ((unsigned int)(d & 127) << 17);
    }
}

// ---------------- build step 5: per-bucket hist+scan+rowptr+place ----------
__global__ void place_merge_kernel(const unsigned int* __restrict__ records,
                                   const int* __restrict__ bptr,
                                   int* __restrict__ rowptr,
                                   int* __restrict__ srcs_sorted,
                                   int N, int nE, int NB) {
    __shared__ int hist[RNODES];
    __shared__ int s[RNODES];
    __shared__ int lcur[RNODES];
    const int b    = blockIdx.x;
    const int base = b * RNODES;
    const int nn   = min(RNODES, N - base);
    const int beg  = bptr[b], end = bptr[b + 1];
    const int t    = threadIdx.x;

    if (t < RNODES) hist[t] = 0;
    __syncthreads();
    for (int i = beg + t; i < end; i += blockDim.x)
        atomicAdd(&hist[records[i] >> 17], 1);
    __syncthreads();

    if (t < RNODES) s[t] = hist[t];
    __syncthreads();
    for (int off = 1; off < RNODES; off <<= 1) {
        int v = (t < RNODES && t >= off) ? s[t - off] : 0;
        __syncthreads();
        if (t < RNODES && t >= off) s[t] += v;
        __syncthreads();
    }
    if (t < nn) {
        int ex = beg + s[t] - hist[t];
        rowptr[base + t] = ex;
        lcur[t] = ex;
    }
    if (b == NB - 1 && t == 0) rowptr[N] = nE;
    __syncthreads();

    for (int i = beg + t; i < end; i += blockDim.x) {
        unsigned int rec = records[i];
        int pos = atomicAdd(&lcur[rec >> 17], 1);
        srcs_sorted[pos] = (int)(rec & 0x1FFFFu);
    }
}

// ---------------- fused: gather(h1) + layer-2 linears ----------------------
// Lane (slot,f): finishes h1[n][f] = h1root + gather, stages relu in LDS,
// then produces one layer-2 output: f<16 -> t2[n][f] (W2rel), f>=16 ->
// h2root[n][f-16] (W2root + b2).
__global__ void gather_fuse32_kernel(const float* __restrict__ t1,
                                     const int* __restrict__ rowptr,
                                     const int* __restrict__ srcs,
                                     const float* __restrict__ h1root,
                                     const float* __restrict__ W2rel,
                                     const float* __restrict__ W2root,
                                     const float* __restrict__ b2,
                                     float* __restrict__ t2,
                                     float* __restrict__ h2root, int N) {
    __shared__ float sx[256];                     // 8 slots x 32 feats
    const int tid = blockIdx.x * blockDim.x + threadIdx.x;
    const int n = tid >> 5;
    const int f = tid & 31;
    const bool valid = (n < N);

    float v = 0.f;
    if (valid) {
        int beg = rowptr[n], end = rowptr[n + 1];
        v = h1root[(size_t)n * 32 + f] + gather_sum<32>(t1 + f, srcs, beg, end);
    }
    sx[threadIdx.x] = fmaxf(v, 0.f);              // relu(h1) staged

    // preload this lane's weight column (overlaps the barrier)
    const int g = f & 15;
    const float* Wc = (f < 16) ? W2rel : W2root;
    float wcol[32];
#pragma unroll
    for (int k = 0; k < 32; ++k) wcol[k] = Wc[k * 16 + g];
    __syncthreads();

    if (valid) {
        const float* xs = &sx[threadIdx.x & ~31]; // slot base (broadcast reads)
        float o = 0.f;
#pragma unroll
        for (int k = 0; k < 32; ++k) o = fmaf(xs[k], wcol[k], o);
        if (f < 16) t2[(size_t)n * 16 + g] = o;
        else        h2root[(size_t)n * 16 + g] = o + b2[g];
    }
}

// ---------------- fused: gather(h2) + layer-3 linears ----------------------
__global__ void gather_fuse16_kernel(const float* __restrict__ t2,
                                     const int* __restrict__ rowptr,
                                     const int* __restrict__ srcs,
                                     const float* __restrict__ h2root,
                                     const float* __restrict__ W3rel,
                                     const float* __restrict__ W3root,
                                     const float* __restrict__ b3,
                                     float* __restrict__ t3,
                                     float* __restrict__ h3root, int N) {
    __shared__ float sx[256];                     // 16 slots x 16 feats
    const int tid = blockIdx.x * blockDim.x + threadIdx.x;
    const int n = tid >> 4;
    const int f = tid & 15;
    const bool valid = (n < N);

    float v = 0.f;
    if (valid) {
        int beg = rowptr[n], end = rowptr[n + 1];
        v = h2root[(size_t)n * 16 + f] + gather_sum<16>(t2 + f, srcs, beg, end);
    }
    sx[threadIdx.x] = fmaxf(v, 0.f);
    __syncthreads();

    if (valid && f < 4) {                          // 4 outputs per node
        const int g = f & 1;
        const float* Wc = (f < 2) ? W3rel : W3root;
        const float* xs = &sx[threadIdx.x & ~15];
        float o = 0.f;
#pragma unroll
        for (int k = 0; k < 16; ++k) o = fmaf(xs[k], Wc[k * 2 + g], o);
        if (f < 2) t3[(size_t)n * 2 + g] = o;
        else       h3root[(size_t)n * 2 + g] = o + b3[g];
    }
}

// ---------------- final: gather(h3) + softmax ------------------------------
__global__ void gather_softmax2_kernel(const float* __restrict__ t3,
                                       const int* __restrict__ rowptr,
                                       const int* __restrict__ srcs,
                                       const float* __restrict__ h3root,
                                       float* __restrict__ out, int N) {
    int tid = blockIdx.x * blockDim.x + threadIdx.x;
    int n = tid >> 1;
    if (n >= N) return;
    int f = tid & 1;
    int beg = rowptr[n], end = rowptr[n + 1];
    float v = h3root[(size_t)n * 2 + f] + gather_sum<2>(t3 + f, srcs, beg, end);
    float o = __shfl_xor(v, 1, 64);                // partner lane = same node
    float m = fmaxf(v, o);
    float ev = __expf(v - m), eo = __expf(o - m);
    out[(size_t)n * 2 + f] = ev / (ev + eo);
}

// ---------------- fallback (R2 atomic path, all-f32) -----------------------
template <int F>
__global__ void scatter_kernel(const float* __restrict__ t,
                               const int* __restrict__ src,
                               const int* __restrict__ dst,
                               float* __restrict__ acc, int nE) {
    int tid = blockIdx.x * blockDim.x + threadIdx.x;
    int e = tid / F;
    if (e >= nE) return;
    int f = tid & (F - 1);
    atomicAdd(acc + (long)dst[e] * F + f, t[(long)src[e] * F + f]);
}

__global__ void softmax2_kernel(const float* __restrict__ h, float* __restrict__ out, int N) {
    int n = blockIdx.x * blockDim.x + threadIdx.x;
    if (n >= N) return;
    float a = h[2 * n], b = h[2 * n + 1];
    float m = fmaxf(a, b);
    float ea = __expf(a - m), eb = __expf(b - m);
    float inv = 1.0f / (ea + eb);
    out[2 * n] = ea * inv;
    out[2 * n + 1] = eb * inv;
}

extern "C" void kernel_launch(void* const* d_in, const int* in_sizes, int n_in,
                              void* d_out, int out_size, void* d_ws, size_t ws_size,
                              hipStream_t stream) {
    const float* z      = (const float*)d_in[0];
    const int*   ei     = (const int*)d_in[1];
    const float* Wrel1  = (const float*)d_in[2];
    const float* Wroot1 = (const float*)d_in[3];
    const float* b1     = (const float*)d_in[4];
    const float* Wrel2  = (const float*)d_in[5];
    const float* Wroot2 = (const float*)d_in[6];
    const float* b2     = (const float*)d_in[7];
    const float* Wrel3  = (const float*)d_in[8];
    const float* Wroot3 = (const float*)d_in[9];
    const float* b3     = (const float*)d_in[10];

    const int N  = in_sizes[0] / 64;   // 100000
    const int nE = in_sizes[1] / 2;    // 1600000
    const int* src = ei;
    const int* dst = ei + nE;
    const int NB = (N + RNODES - 1) / RNODES;   // 782
    const int C  = (nE + CH - 1) / CH;          // 391 chunks

    // Fully disjoint ws layout (~55 MB; harness ws is much larger):
    char* p = (char*)d_ws;
    unsigned int* records = (unsigned int*)p;  p += (size_t)nE * 4;
    int* chunkhist = (int*)p;                  p += (size_t)CMAX * NB_MAX * 4;
    int* gtotal    = (int*)p;                  p += (size_t)NB_MAX * 4;
    int* bptr      = (int*)p;                  p += ((size_t)NB_MAX + 1) * 4;
    int* rowptr    = (int*)p;                  p += ((size_t)N + 1) * 4;
    int* srcs_sorted = (int*)p;                p += (size_t)nE * 4;
    float* t1     = (float*)p;                 p += (size_t)N * 32 * 4;
    float* h1root = (float*)p;                 p += (size_t)N * 32 * 4;
    float* t2     = (float*)p;                 p += (size_t)N * 16 * 4;
    float* h2root = (float*)p;                 p += (size_t)N * 16 * 4;
    float* t3     = (float*)p;                 p += (size_t)N * 2 * 4;
    float* h3root = (float*)p;                 p += (size_t)N * 2 * 4;
    size_t needed = (size_t)(p - (char*)d_ws);

    const int B = 256;
    const int nodeBlocks = (N + B - 1) / B;
    const dim3 linGrid(nodeBlocks, 2);       // y=0: rel->t, y=1: root+b->acc
    const bool packOK = (N <= (1 << 17)) && (NB <= NB_MAX) && (C <= CMAX);

    if (ws_size >= needed && packOK) {
        // ---- build: zero-global-atomic deterministic CSR ----
        hist_chunked_kernel<<<C, 512, 0, stream>>>(dst, chunkhist, nE, NB);
        scan_chunkhist_kernel<<<NB, CMAX, 0, stream>>>(chunkhist, gtotal, C, NB);
        scan_buckets_kernel<<<1, NB_MAX, 0, stream>>>(gtotal, bptr, NB, nE);
        bucketize_det_kernel<<<C, 512, 0, stream>>>(src, dst, chunkhist, bptr, records, nE, NB);
        place_merge_kernel<<<NB, 512, 0, stream>>>(records, bptr, rowptr, srcs_sorted, N, nE, NB);

        // ---- Layer 1: 64 -> 32 ----
        linear2_kernel<64, 32, false><<<linGrid, B, 0, stream>>>(
            z, Wrel1, Wroot1, b1, t1, h1root, N);

        // ---- Layer 2 fused: gather(h1) + linears -> t2, h2root ----
        gather_fuse32_kernel<<<((size_t)N * 32 + B - 1) / B, B, 0, stream>>>(
            t1, rowptr, srcs_sorted, h1root, Wrel2, Wroot2, b2, t2, h2root, N);

        // ---- Layer 3 fused: gather(h2) + linears -> t3, h3root ----
        gather_fuse16_kernel<<<((size_t)N * 16 + B - 1) / B, B, 0, stream>>>(
            t2, rowptr, srcs_sorted, h2root, Wrel3, Wroot3, b3, t3, h3root, N);

        // ---- final: gather(h3) + softmax -> out ----
        gather_softmax2_kernel<<<((size_t)N * 2 + B - 1) / B, B, 0, stream>>>(
            t3, rowptr, srcs_sorted, h3root, (float*)d_out, N);
    } else {
        // ---- fallback: R2 atomic-scatter path (all f32) ----
        linear2_kernel<64, 32, false><<<linGrid, B, 0, stream>>>(z, Wrel1, Wroot1, b1, t1, h1root, N);
        scatter_kernel<32><<<((size_t)nE * 32 + B - 1) / B, B, 0, stream>>>(t1, src, dst, h1root, nE);
        linear2_kernel<32, 16, true><<<linGrid, B, 0, stream>>>(h1root, Wrel2, Wroot2, b2, t2, h2root, N);
        scatter_kernel<16><<<((size_t)nE * 16 + B - 1) / B, B, 0, stream>>>(t2, src, dst, h2root, nE);
        linear2_kernel<16, 2, true><<<linGrid, B, 0, stream>>>(h2root, Wrel3, Wroot3, b3, t3, h3root, N);
        scatter_kernel<2><<<((size_t)nE * 2 + B - 1) / B, B, 0, stream>>>(t3, src, dst, h3root, nE);
        softmax2_kernel<<<nodeBlocks, B, 0, stream>>>(h3root, (float*)d_out, N);
    }
}

// Round 13
// 249.189 us; speedup vs baseline: 1.0760x; 1.0760x over previous
//
#include <hip/hip_runtime.h>
#include <hip/hip_bf16.h>

// 3-layer GraphConv (PyG) + softmax, 100k nodes, 1.6M edges, all f32.
// R2:  f32 global atomics ~306G/s scattered -> pull-gather wins.
// R3:  per-node CSR scatter: 16x write amplification (128us).
// R4:  coarse position-returning cursors: same-address serialization (376us).
// R5:  two-phase placement fixed build; transform store-amp found (94us).
// R6:  LDS-weight transform regressed (LDS-issue bound, 133us). Reverted.
// R7:  linear2 (scalar-path weights, register accs) fixed transform.
// R8:  coarse-first build killed hist_node; reservation chains next (49us).
// R9:  fully deterministic build (zero global atomics). gather32 44.5us.
// R10: staged unroll + occupancy: 248.7us (best). gather at cross-XCD
//      line-duplication floor (85MB fetch vs 102MB naive bound).
// R11: bf16 messages FAILED precision (0.0996>0.02): glorot gains amplify
//      quantization ~20x downstream. f32 mandatory.
// R12: fusing linears into gather epilogues REGRESSED (268us): extra streams
//      evict the random-gather table from L2 (FETCH 85->156MB). Reverted.
// R13: R10 restored verbatim; only change: linear1+hist fused into one
//      launch (independent work, overlap latency with compute); build
//      tables moved to disjoint ws to permit the reorder.

#define RNODES 128
#define NB_MAX 1024
#define CH 4096            // edges per chunk
#define CMAX 512           // max chunks (scan_chunkhist: one chunk/thread)

// ---------------- fused: linear1 (both tasks) + per-chunk histogram --------
// Blocks [0,nb): t1 = z@Wrel1 ; [nb,2nb): h1 = z@Wroot1 + b1 ;
// [2nb, 2nb+C): LDS histogram of chunk c -> chunkhist row.
template <int Fin, int Fout>
__global__ void lin1_hist_kernel(const float* __restrict__ x,
                                 const float* __restrict__ Wrel,
                                 const float* __restrict__ Wroot,
                                 const float* __restrict__ bias,
                                 float* __restrict__ t,
                                 float* __restrict__ acc, int N,
                                 const int* __restrict__ dst,
                                 int* __restrict__ chunkhist,
                                 int nE, int NB, int nodeBlocks) {
    __shared__ int h[NB_MAX];
    const int bx = blockIdx.x;
    if (bx < 2 * nodeBlocks) {
        const bool rootTask = (bx >= nodeBlocks);
        const float* __restrict__ W = rootTask ? Wroot : Wrel;
        float* __restrict__ outp    = rootTask ? acc : t;
        int n = (rootTask ? bx - nodeBlocks : bx) * blockDim.x + threadIdx.x;
        if (n >= N) return;

        float o[Fout];
#pragma unroll
        for (int f = 0; f < Fout; ++f) o[f] = 0.f;
        const float* xr = x + (size_t)n * Fin;
        for (int k0 = 0; k0 < Fin; k0 += 16) {
#pragma unroll
            for (int k = 0; k < 16; k += 4) {
                float4 v = *(const float4*)(xr + k0 + k);
                const float xv[4] = {v.x, v.y, v.z, v.w};
#pragma unroll
                for (int kk = 0; kk < 4; ++kk) {
                    const float* wr = W + (size_t)(k0 + k + kk) * Fout;
#pragma unroll
                    for (int f = 0; f < Fout; ++f)
                        o[f] = fmaf(xv[kk], wr[f], o[f]);
                }
            }
        }
        if (rootTask) {
#pragma unroll
            for (int f = 0; f < Fout; ++f) o[f] += bias[f];
        }
        float* op = outp + (size_t)n * Fout;
#pragma unroll
        for (int f = 0; f < Fout; f += 4)
            *(float4*)(op + f) = make_float4(o[f], o[f + 1], o[f + 2], o[f + 3]);
    } else {
        const int c  = bx - 2 * nodeBlocks;
        const int e0 = c * CH, e1 = min(e0 + CH, nE);
        for (int b = threadIdx.x; b < NB; b += blockDim.x) h[b] = 0;
        __syncthreads();
        for (int e = e0 + threadIdx.x; e < e1; e += blockDim.x)
            atomicAdd(&h[dst[e] >> 7], 1);
        __syncthreads();
        for (int b = threadIdx.x; b < NB; b += blockDim.x)
            chunkhist[(size_t)c * NB + b] = h[b];
    }
}

// ---------------- linear: out = act(x) @ W (+ bias for root task) ----------
template <int Fin, int Fout, bool RELU>
__global__ void linear2_kernel(const float* __restrict__ x,
                               const float* __restrict__ Wrel,
                               const float* __restrict__ Wroot,
                               const float* __restrict__ bias,
                               float* __restrict__ t,
                               float* __restrict__ acc, int N) {
    const bool rootTask = (blockIdx.y != 0);
    const float* __restrict__ W = rootTask ? Wroot : Wrel;
    float* __restrict__ outp    = rootTask ? acc : t;

    int n = blockIdx.x * blockDim.x + threadIdx.x;
    if (n >= N) return;

    float o[Fout];
#pragma unroll
    for (int f = 0; f < Fout; ++f) o[f] = 0.f;

    const float* xr = x + (size_t)n * Fin;
    for (int k0 = 0; k0 < Fin; k0 += 16) {
#pragma unroll
        for (int k = 0; k < 16; k += 4) {
            float4 v = *(const float4*)(xr + k0 + k);
            if (RELU) {
                v.x = fmaxf(v.x, 0.f); v.y = fmaxf(v.y, 0.f);
                v.z = fmaxf(v.z, 0.f); v.w = fmaxf(v.w, 0.f);
            }
            const float xv[4] = {v.x, v.y, v.z, v.w};
#pragma unroll
            for (int kk = 0; kk < 4; ++kk) {
                const float* wr = W + (size_t)(k0 + k + kk) * Fout;
#pragma unroll
                for (int f = 0; f < Fout; ++f)
                    o[f] = fmaf(xv[kk], wr[f], o[f]);
            }
        }
    }
    if (rootTask) {
#pragma unroll
        for (int f = 0; f < Fout; ++f) o[f] += bias[f];
    }
    float* op = outp + (size_t)n * Fout;
    if constexpr (Fout >= 4) {
#pragma unroll
        for (int f = 0; f < Fout; f += 4)
            *(float4*)(op + f) = make_float4(o[f], o[f + 1], o[f + 2], o[f + 3]);
    } else {
        *(float2*)op = make_float2(o[0], o[1]);
    }
}

// ---------------- build step 2: column scan (per bucket over chunks) -------
__global__ void scan_chunkhist_kernel(int* __restrict__ chunkhist,
                                      int* __restrict__ gtotal,
                                      int C, int NB) {
    __shared__ int s[CMAX];
    const int b = blockIdx.x;
    const int t = threadIdx.x;
    int v = (t < C) ? chunkhist[(size_t)t * NB + b] : 0;
    s[t] = v;
    __syncthreads();
    for (int off = 1; off < CMAX; off <<= 1) {
        int u = (t >= off) ? s[t - off] : 0;
        __syncthreads();
        s[t] += u;
        __syncthreads();
    }
    if (t < C) chunkhist[(size_t)t * NB + b] = s[t] - v;   // exclusive
    if (t == CMAX - 1) gtotal[b] = s[t];
}

// ---------------- build step 3: bucket scan (single block) -----------------
__global__ void scan_buckets_kernel(const int* __restrict__ gtotal,
                                    int* __restrict__ bptr, int NB, int nE) {
    __shared__ int s[NB_MAX];
    int t = threadIdx.x;
    int own = (t < NB) ? gtotal[t] : 0;
    s[t] = own;
    __syncthreads();
    for (int off = 1; off < NB_MAX; off <<= 1) {
        int v = (t >= off) ? s[t - off] : 0;
        __syncthreads();
        s[t] += v;
        __syncthreads();
    }
    if (t < NB) bptr[t] = s[t] - own;
    if (t == 0) bptr[NB] = nE;
}

// ---------------- build step 4: deterministic placement --------------------
__global__ void bucketize_det_kernel(const int* __restrict__ src,
                                     const int* __restrict__ dst,
                                     const int* __restrict__ chunkpre,
                                     const int* __restrict__ bptr,
                                     unsigned int* __restrict__ records,
                                     int nE, int NB) {
    __shared__ int lcur[NB_MAX];
    const int c  = blockIdx.x;
    const int e0 = c * CH, e1 = min(e0 + CH, nE);
    for (int b = threadIdx.x; b < NB; b += blockDim.x)
        lcur[b] = bptr[b] + chunkpre[(size_t)c * NB + b];
    __syncthreads();
    for (int e = e0 + threadIdx.x; e < e1; e += blockDim.x) {
        int d = dst[e];
        int b = d >> 7;
        int pos = atomicAdd(&lcur[b], 1);                  // LDS-only atomic
        records[pos] = (unsigned int)src[e] | ((unsigned int)(d & 127) << 17);
    }
}

// ---------------- build step 5: per-bucket hist+scan+rowptr+place ----------
__global__ void place_merge_kernel(const unsigned int* __restrict__ records,
                                   const int* __restrict__ bptr,
                                   int* __restrict__ rowptr,
                                   int* __restrict__ srcs_sorted,
                                   int N, int nE, int NB) {
    __shared__ int hist[RNODES];
    __shared__ int s[RNODES];
    __shared__ int lcur[RNODES];
    const int b    = blockIdx.x;
    const int base = b * RNODES;
    const int nn   = min(RNODES, N - base);
    const int beg  = bptr[b], end = bptr[b + 1];
    const int t    = threadIdx.x;

    if (t < RNODES) hist[t] = 0;
    __syncthreads();
    for (int i = beg + t; i < end; i += blockDim.x)
        atomicAdd(&hist[records[i] >> 17], 1);
    __syncthreads();

    if (t < RNODES) s[t] = hist[t];
    __syncthreads();
    for (int off = 1; off < RNODES; off <<= 1) {
        int v = (t < RNODES && t >= off) ? s[t - off] : 0;
        __syncthreads();
        if (t < RNODES && t >= off) s[t] += v;
        __syncthreads();
    }
    if (t < nn) {
        int ex = beg + s[t] - hist[t];
        rowptr[base + t] = ex;
        lcur[t] = ex;
    }
    if (b == NB - 1 && t == 0) rowptr[N] = nE;
    __syncthreads();

    for (int i = beg + t; i < end; i += blockDim.x) {
        unsigned int rec = records[i];
        int pos = atomicAdd(&lcur[rec >> 17], 1);
        srcs_sorted[pos] = (int)(rec & 0x1FFFFu);
    }
}

// ---------------- pull aggregation: staged unroll 16/4/1 -------------------
template <int F, bool SOFTMAX>
__global__ void gather_agg_kernel(const float* __restrict__ t,
                                  const int* __restrict__ rowptr,
                                  const int* __restrict__ srcs,
                                  const float* __restrict__ rootacc,
                                  float* __restrict__ out, int N) {
    int tid = blockIdx.x * blockDim.x + threadIdx.x;
    int n = tid / F;
    if (n >= N) return;
    int f = tid & (F - 1);
    const float* tf = t + f;
    int beg = rowptr[n], end = rowptr[n + 1];
    float sum = 0.0f;
    int e = beg;
    for (; e + 16 <= end; e += 16) {
        int s[16];
        float v[16];
#pragma unroll
        for (int u = 0; u < 16; ++u) s[u] = srcs[e + u];
#pragma unroll
        for (int u = 0; u < 16; ++u) v[u] = tf[(long)s[u] * F];
#pragma unroll
        for (int u = 0; u < 16; ++u) sum += v[u];
    }
    for (; e + 4 <= end; e += 4) {
        int s[4];
        float v[4];
#pragma unroll
        for (int u = 0; u < 4; ++u) s[u] = srcs[e + u];
#pragma unroll
        for (int u = 0; u < 4; ++u) v[u] = tf[(long)s[u] * F];
        sum += (v[0] + v[1]) + (v[2] + v[3]);
    }
    for (; e < end; ++e) sum += tf[(long)srcs[e] * F];

    float v = rootacc[(long)n * F + f] + sum;
    if (!SOFTMAX) {
        out[(long)n * F + f] = v;
    } else {
        float o = __shfl_xor(v, 1, 64);
        float m = fmaxf(v, o);
        float ev = __expf(v - m), eo = __expf(o - m);
        out[(long)n * F + f] = ev / (ev + eo);
    }
}

// ---------------- fallback (R2 atomic path) --------------------------------
template <int F>
__global__ void scatter_kernel(const float* __restrict__ t,
                               const int* __restrict__ src,
                               const int* __restrict__ dst,
                               float* __restrict__ acc, int nE) {
    int tid = blockIdx.x * blockDim.x + threadIdx.x;
    int e = tid / F;
    if (e >= nE) return;
    int f = tid & (F - 1);
    atomicAdd(acc + (long)dst[e] * F + f, t[(long)src[e] * F + f]);
}

__global__ void softmax2_kernel(const float* __restrict__ h, float* __restrict__ out, int N) {
    int n = blockIdx.x * blockDim.x + threadIdx.x;
    if (n >= N) return;
    float a = h[2 * n], b = h[2 * n + 1];
    float m = fmaxf(a, b);
    float ea = __expf(a - m), eb = __expf(b - m);
    float inv = 1.0f / (ea + eb);
    out[2 * n] = ea * inv;
    out[2 * n + 1] = eb * inv;
}

extern "C" void kernel_launch(void* const* d_in, const int* in_sizes, int n_in,
                              void* d_out, int out_size, void* d_ws, size_t ws_size,
                              hipStream_t stream) {
    const float* z      = (const float*)d_in[0];
    const int*   ei     = (const int*)d_in[1];
    const float* Wrel1  = (const float*)d_in[2];
    const float* Wroot1 = (const float*)d_in[3];
    const float* b1     = (const float*)d_in[4];
    const float* Wrel2  = (const float*)d_in[5];
    const float* Wroot2 = (const float*)d_in[6];
    const float* b2     = (const float*)d_in[7];
    const float* Wrel3  = (const float*)d_in[8];
    const float* Wroot3 = (const float*)d_in[9];
    const float* b3     = (const float*)d_in[10];

    const int N  = in_sizes[0] / 64;   // 100000
    const int nE = in_sizes[1] / 2;    // 1600000
    const int* src = ei;
    const int* dst = ei + nE;
    const int NB = (N + RNODES - 1) / RNODES;   // 782
    const int C  = (nE + CH - 1) / CH;          // 391 chunks

    // Float regions (ping-pong, 12.8 MB each) — R10 aliasing for the hot
    // arrays (t2 overwrites dead t1; t3/h3 overwrite dead h1):
    //   regionA: t1[N*32] -> { t2[N*16] | h2[N*16] }
    //   regionB: h1[N*32] -> { t3[N*2] | h3[N*2] }
    float* regionA = (float*)d_ws;
    float* regionB = regionA + (size_t)N * 32;
    float* t1 = regionA;
    float* h1 = regionB;
    float* t2 = regionA;
    float* h2 = regionA + (size_t)N * 16;
    float* t3 = regionB;
    float* h3 = regionB + (size_t)N * 2;

    // Disjoint int region (build tables can no longer alias t1/h1 because
    // linear1 now runs before the build completes):
    int* ibase       = (int*)(regionB + (size_t)N * 32);
    int* rowptr      = ibase;                              // [N+1]
    int* srcs_sorted = rowptr + N + 1;                     // [nE]
    unsigned int* records = (unsigned int*)(srcs_sorted + nE);  // [nE]
    int* chunkhist   = (int*)(records + nE);               // [CMAX][NB_MAX]
    int* gtotal      = chunkhist + (size_t)CMAX * NB_MAX;  // [NB_MAX]
    int* bptr        = gtotal + NB_MAX;                    // [NB_MAX+1]

    size_t needed = (size_t)N * 64 * sizeof(float)
                  + ((size_t)N + 1 + 2 * (size_t)nE
                     + (size_t)CMAX * NB_MAX + 2 * NB_MAX + 1) * sizeof(int);

    const int B = 256;
    const int nodeBlocks = (N + B - 1) / B;
    const dim3 linGrid(nodeBlocks, 2);       // y=0: rel->t, y=1: root+b->acc
    const bool packOK = (N <= (1 << 17)) && (NB <= NB_MAX) && (C <= CMAX);

    if (ws_size >= needed && packOK) {
        // ---- fused: linear1 (both tasks) + chunk histograms ----
        lin1_hist_kernel<64, 32><<<2 * nodeBlocks + C, B, 0, stream>>>(
            z, Wrel1, Wroot1, b1, t1, h1, N, dst, chunkhist, nE, NB, nodeBlocks);
        // ---- build: deterministic CSR (zero global atomics) ----
        scan_chunkhist_kernel<<<NB, CMAX, 0, stream>>>(chunkhist, gtotal, C, NB);
        scan_buckets_kernel<<<1, NB_MAX, 0, stream>>>(gtotal, bptr, NB, nE);
        bucketize_det_kernel<<<C, 512, 0, stream>>>(src, dst, chunkhist, bptr, records, nE, NB);
        place_merge_kernel<<<NB, 512, 0, stream>>>(records, bptr, rowptr, srcs_sorted, N, nE, NB);

        // ---- Layer 1 gather ----
        gather_agg_kernel<32, false><<<((size_t)N * 32 + B - 1) / B, B, 0, stream>>>(
            t1, rowptr, srcs_sorted, h1, h1, N);

        // ---- Layer 2: 32 -> 16 ----
        linear2_kernel<32, 16, true><<<linGrid, B, 0, stream>>>(h1, Wrel2, Wroot2, b2, t2, h2, N);
        gather_agg_kernel<16, false><<<((size_t)N * 16 + B - 1) / B, B, 0, stream>>>(
            t2, rowptr, srcs_sorted, h2, h2, N);

        // ---- Layer 3: 16 -> 2, softmax fused ----
        linear2_kernel<16, 2, true><<<linGrid, B, 0, stream>>>(h2, Wrel3, Wroot3, b3, t3, h3, N);
        gather_agg_kernel<2, true><<<((size_t)N * 2 + B - 1) / B, B, 0, stream>>>(
            t3, rowptr, srcs_sorted, h3, (float*)d_out, N);
    } else {
        // ---- fallback: R2 atomic-scatter path ----
        linear2_kernel<64, 32, false><<<linGrid, B, 0, stream>>>(z, Wrel1, Wroot1, b1, t1, h1, N);
        scatter_kernel<32><<<((size_t)nE * 32 + B - 1) / B, B, 0, stream>>>(t1, src, dst, h1, nE);
        linear2_kernel<32, 16, true><<<linGrid, B, 0, stream>>>(h1, Wrel2, Wroot2, b2, t2, h2, N);
        scatter_kernel<16><<<((size_t)nE * 16 + B - 1) / B, B, 0, stream>>>(t2, src, dst, h2, nE);
        linear2_kernel<16, 2, true><<<linGrid, B, 0, stream>>>(h2, Wrel3, Wroot3, b3, t3, h3, N);
        scatter_kernel<2><<<((size_t)nE * 2 + B - 1) / B, B, 0, stream>>>(t3, src, dst, h3, nE);
        softmax2_kernel<<<nodeBlocks, B, 0, stream>>>(h3, (float*)d_out, N);
    }
}